// Round 11
// baseline (109.723 us; speedup 1.0000x reference)
//
#include <hip/hip_runtime.h>

#define Bn 4096
#define Dn 66
#define Hn 512

typedef __attribute__((ext_vector_type(8))) short short8;
typedef __attribute__((ext_vector_type(4))) float f32x4;

__device__ __forceinline__ unsigned short f2bf(float x) {
    union { float f; unsigned u; } v; v.f = x;
    unsigned r = v.u + 0x7fffu + ((v.u >> 16) & 1u);   // RNE
    return (unsigned short)(r >> 16);
}
__device__ __forceinline__ float bf2f(unsigned short h) {
    union { float f; unsigned u; } v; v.u = ((unsigned)h) << 16; return v.f;
}

// ============ k_pack (74 blocks x 512) — unchanged from R10 ============
__global__ __launch_bounds__(512, 2) void k_pack(
    const float* __restrict__ W1, const float* __restrict__ W2,
    const float* __restrict__ W3,
    unsigned short* __restrict__ W2P, unsigned short* __restrict__ CmP,
    unsigned short* __restrict__ W3P)
{
    __shared__ float sW3[16*68];
    const int bid = blockIdx.x, tid = threadIdx.x;
    const int lane = tid & 63, wv = tid >> 6;

    if (bid < 64) {
        const int ct = bid >> 1;
        {
            const int r = tid >> 5, ii = tid & 31;
            const float* src = &W3[(size_t)(ct*16 + r)*Dn];
            sW3[r*68 + ii] = src[ii];
            sW3[r*68 + ii + 32] = src[ii + 32];
            if (ii < 2) sW3[r*68 + ii + 64] = src[ii + 64];
        }
        __syncthreads();
        const int ks = (bid & 1)*8 + wv;
        const int n = lane & 15, kg = lane >> 4;
        const int c = ct*16 + n;
        const int abase = ks*32 + kg*8;
        float w2v[8], m[8];
        #pragma unroll
        for (int j = 0; j < 8; ++j) {
            w2v[j] = W2[(size_t)(abase + j)*Hn + c];
            m[j] = 0.f;
        }
        #pragma unroll 2
        for (int i = 0; i < Dn; ++i) {
            const float w3 = sW3[n*68 + i];
            const float4 w1a = *(const float4*)&W1[(size_t)i*Hn + abase];
            const float4 w1b = *(const float4*)&W1[(size_t)i*Hn + abase + 4];
            m[0] = fmaf(w3, w1a.x, m[0]); m[1] = fmaf(w3, w1a.y, m[1]);
            m[2] = fmaf(w3, w1a.z, m[2]); m[3] = fmaf(w3, w1a.w, m[3]);
            m[4] = fmaf(w3, w1b.x, m[4]); m[5] = fmaf(w3, w1b.y, m[5]);
            m[6] = fmaf(w3, w1b.z, m[6]); m[7] = fmaf(w3, w1b.w, m[7]);
        }
        short8 pw, pc;
        #pragma unroll
        for (int j = 0; j < 8; ++j) {
            pw[j] = (short)f2bf(w2v[j]);
            pc[j] = (short)f2bf(w2v[j] * m[j]);
        }
        const size_t off = ((size_t)(ct*16 + ks)*64 + lane)*8;
        *(short8*)&W2P[off] = pw;
        *(short8*)&CmP[off] = pc;
    } else {
        const int tix = (bid - 64)*8 + wv;
        if (tix < 80) {
            const int ks = tix & 15;
            const int n = lane & 15, kg = lane >> 4;
            const int j_out = (tix >> 4)*16 + n;
            const int abase = ks*32 + kg*8;
            short8 p;
            #pragma unroll
            for (int j = 0; j < 8; ++j)
                p[j] = (j_out < Dn) ? (short)f2bf(W3[(size_t)(abase + j)*Dn + j_out]) : (short)0;
            *(short8*)&W3P[((size_t)tix*64 + lane)*8] = p;
        }
    }
}

// ============ k_main: 32 rows x 256 out-cols per block, grid 256 x 1024 ============
// A-frag LDS: tile (rtl, ks) at ((rtl*16 + ks)*64 + lane)*8   (rtl = 0/1 -> rows 0-15/16-31)
// h2-frag LDS (aliased): tile (rtl, ksl) at ((rtl*8 + ksl)*64 + lane)*8, ksl local to half
__global__ __launch_bounds__(1024, 4) void k_main(
    const float* __restrict__ xs, const float* __restrict__ tt,
    const float* __restrict__ W1, const float* __restrict__ b1,
    const unsigned short* __restrict__ W2P, const unsigned short* __restrict__ CmP,
    const float* __restrict__ b2,
    const unsigned short* __restrict__ W3P, const float* __restrict__ b3,
    float* __restrict__ outP, float* __restrict__ dpP)
{
    __shared__ __align__(16) unsigned short sA[3*16384];  // h1hi|h1lo|s1' (96 KB); h2 aliases front
    __shared__ float sX[67*32];
    __shared__ float sRed[16*32];

    const int tid = threadIdx.x, lane = tid & 63, wv = tid >> 6;   // wv 0..15
    const int rg32 = blockIdx.x >> 1, half = blockIdx.x & 1;
    const int r0 = rg32*32;
    const int n = lane & 15, kg = lane >> 4;
    const int rot = (blockIdx.x >> 3) & 15;

    // ---- stage x^T (row 66 = t), 32 batch rows ----
    for (int idx = tid; idx < 67*32; idx += 1024) {
        const int i = idx >> 5, r = idx & 31;
        sX[idx] = (i < Dn) ? xs[(size_t)(r0+r)*Dn + i] : tt[r0+r];
    }
    __syncthreads();

    // ---- phase A: z1 fp32; wave wv -> cols [wv*32, wv*32+32), 4 rows/lane ----
    {
        const int rg = lane & 7, cg = lane >> 3;
        const int c0 = wv*32 + cg*4;
        const int irot = (blockIdx.x >> 3) & 31;
        float z[4][4];
        {
            const float4 b4 = *(const float4*)&b1[c0];
            #pragma unroll
            for (int rr = 0; rr < 4; ++rr) { z[rr][0]=b4.x; z[rr][1]=b4.y; z[rr][2]=b4.z; z[rr][3]=b4.w; }
        }
        #pragma unroll 2
        for (int s = 0; s < 67; ++s) {
            int i = s + irot; if (i >= 67) i -= 67;
            const float2 x0 = *(const float2*)&sX[i*32 + 2*rg];
            const float2 x1 = *(const float2*)&sX[i*32 + 16 + 2*rg];
            const float4 wA = *(const float4*)&W1[(size_t)i*Hn + c0];
            const float ww[4] = {wA.x, wA.y, wA.z, wA.w};
            #pragma unroll
            for (int j = 0; j < 4; ++j) {
                z[0][j] = fmaf(x0.x, ww[j], z[0][j]);
                z[1][j] = fmaf(x0.y, ww[j], z[1][j]);
                z[2][j] = fmaf(x1.x, ww[j], z[2][j]);
                z[3][j] = fmaf(x1.y, ww[j], z[3][j]);
            }
        }
        const int kgrp = cg >> 1, joff = (cg & 1)*4;
        #pragma unroll
        for (int rr = 0; rr < 4; ++rr) {
            const int rtl = rr >> 1;                 // 0: rows 0-15, 1: rows 16-31
            const int m = 2*(lane & 7) + (rr & 1);   // row within tile
            ushort4 phi, plo, ps;
            unsigned short* PH = (unsigned short*)&phi;
            unsigned short* PL = (unsigned short*)&plo;
            unsigned short* PS = (unsigned short*)&ps;
            #pragma unroll
            for (int j = 0; j < 4; ++j) {
                const float zv = z[rr][j];
                const float sg = 1.f / (1.f + __expf(-zv));
                const float h  = zv * sg;
                const float sp = sg * (1.f + zv * (1.f - sg));
                const unsigned short hh = f2bf(h);
                PH[j] = hh;
                PL[j] = f2bf(h - bf2f(hh));
                PS[j] = f2bf(sp);
            }
            const int off = ((rtl*16 + wv)*64 + m + 16*kgrp)*8 + joff;
            *(ushort4*)&sA[off]          = phi;
            *(ushort4*)&sA[16384 + off]  = plo;
            *(ushort4*)&sA[32768 + off]  = ps;
        }
    }
    __syncthreads();

    // ---- phase B: z2/v MFMA; wave wv -> ctile ctb = half*16 + wv; K = all 16 ks ----
    const int ctb = half*16 + wv;
    f32x4 zac[2], vac[2];
    {
        const float bz = b2[ctb*16 + n];
        zac[0] = (f32x4){bz, bz, bz, bz};
        zac[1] = (f32x4){bz, bz, bz, bz};
        vac[0] = (f32x4){0.f, 0.f, 0.f, 0.f};
        vac[1] = (f32x4){0.f, 0.f, 0.f, 0.f};
    }
    #pragma unroll 2
    for (int s = 0; s < 16; ++s) {
        const int ks = (s + rot) & 15;
        const size_t wo = ((size_t)(ctb*16 + ks)*64 + lane)*8;
        const short8 wf = *(const short8*)&W2P[wo];
        const short8 qf = *(const short8*)&CmP[wo];
        #pragma unroll
        for (int rtl = 0; rtl < 2; ++rtl) {
            const int ao = ((rtl*16 + ks)*64 + lane)*8;
            const short8 ahi = *(const short8*)&sA[ao];
            const short8 alo = *(const short8*)&sA[16384 + ao];
            const short8 as1 = *(const short8*)&sA[32768 + ao];
            zac[rtl] = __builtin_amdgcn_mfma_f32_16x16x32_bf16(ahi, wf, zac[rtl], 0, 0, 0);
            zac[rtl] = __builtin_amdgcn_mfma_f32_16x16x32_bf16(alo, wf, zac[rtl], 0, 0, 0);
            vac[rtl] = __builtin_amdgcn_mfma_f32_16x16x32_bf16(as1, qf, vac[rtl], 0, 0, 0);
        }
    }
    __syncthreads();   // all h1/s1 reads done before h2 aliases sA front

    // ---- epilogue: h2 hi/lo -> sA[0..8192]/sA[8192..16384] (local-half frags); dp ----
    float dp[2][4] = {{0.f,0.f,0.f,0.f},{0.f,0.f,0.f,0.f}};
    {
        const int c_local = wv*16 + n;               // col within the half (0..255)
        const int ksl = c_local >> 5, kg2 = (c_local >> 3) & 3, j2 = c_local & 7;
        #pragma unroll
        for (int rtl = 0; rtl < 2; ++rtl) {
            #pragma unroll
            for (int q = 0; q < 4; ++q) {
                const float z2 = zac[rtl][q];
                const float sg = 1.f / (1.f + __expf(-z2));
                const float h2 = z2 * sg;
                dp[rtl][q] = fmaf(sg * (1.f + z2 * (1.f - sg)), vac[rtl][q], dp[rtl][q]);
                const unsigned short hh = f2bf(h2);
                const int o = ((rtl*8 + ksl)*64 + (kg*4 + q) + 16*kg2)*8 + j2;
                sA[o] = hh;
                sA[8192 + o] = f2bf(h2 - bf2f(hh));
            }
        }
    }
    #pragma unroll
    for (int rtl = 0; rtl < 2; ++rtl) {
        #pragma unroll
        for (int q = 0; q < 4; ++q) {
            float v = dp[rtl][q];
            v += __shfl_xor(v, 1, 64);
            v += __shfl_xor(v, 2, 64);
            v += __shfl_xor(v, 4, 64);
            v += __shfl_xor(v, 8, 64);
            if (n == 0) sRed[wv*32 + rtl*16 + kg*4 + q] = v;
        }
    }
    __syncthreads();

    // ---- divergence partial for this half ----
    if (tid < 32) {
        float s = 0.f;
        #pragma unroll
        for (int q = 0; q < 16; ++q) s += sRed[q*32 + tid];
        dpP[(size_t)half*Bn + r0 + tid] = s;
    }

    // ---- phase C: partial out = h2_half @ W3_half (+ b3 in half 0); waves 0..9 ----
    if (wv < 10) {
        const int rtl = wv / 5, jt = wv % 5;
        const int j = jt*16 + n;
        const float bj = (j < Dn && half == 0) ? b3[j] : 0.f;
        f32x4 oac = (f32x4){bj, bj, bj, bj};
        #pragma unroll 4
        for (int s = 0; s < 8; ++s) {
            const int ksl = (s + (rot & 7)) & 7;
            const int ks_g = half*8 + ksl;
            const int ao = ((rtl*8 + ksl)*64 + lane)*8;
            const short8 ahi = *(const short8*)&sA[ao];
            const short8 alo = *(const short8*)&sA[8192 + ao];
            const short8 wf  = *(const short8*)&W3P[((size_t)(jt*16 + ks_g)*64 + lane)*8];
            oac = __builtin_amdgcn_mfma_f32_16x16x32_bf16(ahi, wf, oac, 0, 0, 0);
            oac = __builtin_amdgcn_mfma_f32_16x16x32_bf16(alo, wf, oac, 0, 0, 0);
        }
        if (j < Dn) {
            #pragma unroll
            for (int q = 0; q < 4; ++q)
                outP[(size_t)half*Bn*Dn + (size_t)(r0 + rtl*16 + kg*4 + q)*Dn + j] = oac[q];
        }
    }
}

// ============ k_final: out = outP0 + outP1 ; -div = -(dp0 + dp1) ============
__global__ __launch_bounds__(256) void k_final(
    const float* __restrict__ outP, const float* __restrict__ dpP,
    float* __restrict__ out)
{
    const int bid = blockIdx.x, tid = threadIdx.x;
    if (bid < 264) {
        const size_t t = (size_t)bid*256 + tid;      // 264*256 = 67584 = Bn*Dn/4
        const float4 a = ((const float4*)outP)[t];
        const float4 b = ((const float4*)(outP + (size_t)Bn*Dn))[t];
        float4 r; r.x = a.x+b.x; r.y = a.y+b.y; r.z = a.z+b.z; r.w = a.w+b.w;
        ((float4*)out)[t] = r;
    } else {
        const int r = (bid - 264)*256 + tid;         // 16*256 = 4096
        out[(size_t)Bn*Dn + r] = -(dpP[r] + dpP[Bn + r]);
    }
}

extern "C" void kernel_launch(void* const* d_in, const int* in_sizes, int n_in,
                              void* d_out, int out_size, void* d_ws, size_t ws_size,
                              hipStream_t stream)
{
    const float* xs = (const float*)d_in[0];
    const float* t  = (const float*)d_in[1];
    const float* W1 = (const float*)d_in[2];
    const float* b1 = (const float*)d_in[3];
    const float* W2 = (const float*)d_in[4];
    const float* b2 = (const float*)d_in[5];
    const float* W3 = (const float*)d_in[6];
    const float* b3 = (const float*)d_in[7];
    float* out = (float*)d_out;

    char* ws = (char*)d_ws;
    unsigned short* W2P = (unsigned short*)(ws);                 // 512 KB
    unsigned short* CmP = (unsigned short*)(ws + 524288);        // 512 KB
    unsigned short* W3P = (unsigned short*)(ws + 1048576);       // 80 KB
    float*         outP = (float*)(ws + 1130496);                // 2 x 1.03 MB
    float*          dpP = (float*)(ws + 1130496 + 2*(size_t)Bn*Dn*4);  // 32 KB

    k_pack <<<74,  512,  0, stream>>>(W1, W2, W3, W2P, CmP, W3P);
    k_main <<<256, 1024, 0, stream>>>(xs, t, W1, b1, W2P, CmP, b2, W3P, b3, outP, dpP);
    k_final<<<280, 256,  0, stream>>>(outP, dpP, out);
}

// Round 12
// 108.747 us; speedup vs baseline: 1.0090x; 1.0090x over previous
//
#include <hip/hip_runtime.h>

#define Bn 4096
#define Dn 66
#define Hn 512

typedef __attribute__((ext_vector_type(8))) short short8;
typedef __attribute__((ext_vector_type(4))) float f32x4;

__device__ __forceinline__ unsigned short f2bf(float x) {
    union { float f; unsigned u; } v; v.f = x;
    unsigned r = v.u + 0x7fffu + ((v.u >> 16) & 1u);   // RNE
    return (unsigned short)(r >> 16);
}
__device__ __forceinline__ float bf2f(unsigned short h) {
    union { float f; unsigned u; } v; v.u = ((unsigned)h) << 16; return v.f;
}

// Layouts:
//   A-frag (block-local) tile ks: lane l holds A[(l&15)][ks*32 + (l>>4)*8 + j]
//       at (ks*64 + l)*8 + j                  -> conflict-free ds_read_b128
//   WQ interleaved B-frag tile (ct, ks): lane l holds W2-frag at
//       ((ct*16+ks)*64 + l)*16 + 0..7 and Cm-frag at +8..15  -> 2KB contiguous per wave
//   W3P B-frag tile (jt, ks): ((jt*16+ks)*64 + l)*8 + j

// ============ k_pack (74 blocks x 512) ============
__global__ __launch_bounds__(512, 2) void k_pack(
    const float* __restrict__ W1, const float* __restrict__ W2,
    const float* __restrict__ W3,
    unsigned short* __restrict__ WQ, unsigned short* __restrict__ W3P)
{
    __shared__ float sW3[16*68];
    const int bid = blockIdx.x, tid = threadIdx.x;
    const int lane = tid & 63, wv = tid >> 6;

    if (bid < 64) {
        const int ct = bid >> 1;
        {
            const int r = tid >> 5, ii = tid & 31;
            const float* src = &W3[(size_t)(ct*16 + r)*Dn];
            sW3[r*68 + ii] = src[ii];
            sW3[r*68 + ii + 32] = src[ii + 32];
            if (ii < 2) sW3[r*68 + ii + 64] = src[ii + 64];
        }
        __syncthreads();
        const int ks = (bid & 1)*8 + wv;
        const int n = lane & 15, kg = lane >> 4;
        const int c = ct*16 + n;
        const int abase = ks*32 + kg*8;
        float w2v[8], m[8];
        #pragma unroll
        for (int j = 0; j < 8; ++j) {
            w2v[j] = W2[(size_t)(abase + j)*Hn + c];
            m[j] = 0.f;
        }
        #pragma unroll 2
        for (int i = 0; i < Dn; ++i) {
            const float w3 = sW3[n*68 + i];
            const float4 w1a = *(const float4*)&W1[(size_t)i*Hn + abase];
            const float4 w1b = *(const float4*)&W1[(size_t)i*Hn + abase + 4];
            m[0] = fmaf(w3, w1a.x, m[0]); m[1] = fmaf(w3, w1a.y, m[1]);
            m[2] = fmaf(w3, w1a.z, m[2]); m[3] = fmaf(w3, w1a.w, m[3]);
            m[4] = fmaf(w3, w1b.x, m[4]); m[5] = fmaf(w3, w1b.y, m[5]);
            m[6] = fmaf(w3, w1b.z, m[6]); m[7] = fmaf(w3, w1b.w, m[7]);
        }
        short8 pw, pc;
        #pragma unroll
        for (int j = 0; j < 8; ++j) {
            pw[j] = (short)f2bf(w2v[j]);
            pc[j] = (short)f2bf(w2v[j] * m[j]);
        }
        const size_t off = ((size_t)(ct*16 + ks)*64 + lane)*16;
        *(short8*)&WQ[off]     = pw;
        *(short8*)&WQ[off + 8] = pc;
    } else {
        const int tix = (bid - 64)*8 + wv;
        if (tix < 80) {
            const int ks = tix & 15;
            const int n = lane & 15, kg = lane >> 4;
            const int j_out = (tix >> 4)*16 + n;
            const int abase = ks*32 + kg*8;
            short8 p;
            #pragma unroll
            for (int j = 0; j < 8; ++j)
                p[j] = (j_out < Dn) ? (short)f2bf(W3[(size_t)(abase + j)*Dn + j_out]) : (short)0;
            *(short8*)&W3P[((size_t)tix*64 + lane)*8] = p;
        }
    }
}

// ============ k_main: fused, grid 256 x 1024; rotation + weight prefetch ============
__global__ __launch_bounds__(1024, 4) void k_main(
    const float* __restrict__ xs, const float* __restrict__ tt,
    const float* __restrict__ W1, const float* __restrict__ b1,
    const unsigned short* __restrict__ WQ, const float* __restrict__ b2,
    const unsigned short* __restrict__ W3P, const float* __restrict__ b3,
    float* __restrict__ out)
{
    __shared__ __align__(16) unsigned short sA[3*8192];  // h1hi|h1lo|s1' ; then h2hi|h2lo
    __shared__ float sX[67*16];
    __shared__ float sRed[16*16];

    const int tid = threadIdx.x, lane = tid & 63, wv = tid >> 6;   // wv 0..15
    const int rt = blockIdx.x, r0 = rt*16;
    const int n = lane & 15, kg = lane >> 4;
    const int rot = (blockIdx.x >> 3) & 15;

    // ---- stage x^T (row 66 = t) ----
    for (int idx = tid; idx < 67*16; idx += 1024) {
        const int i = idx >> 4, r = idx & 15;
        sX[idx] = (i < Dn) ? xs[(size_t)(r0+r)*Dn + i] : tt[r0+r];
    }
    __syncthreads();

    // ---- phase A: z1 (fp32); wave wv owns cols [wv*32, wv*32+32); rotated i-start ----
    {
        const int rg = lane & 7, cg = lane >> 3;
        const int c0 = wv*32 + cg*4;
        const int irot = (blockIdx.x >> 3) & 31;
        float z[2][4];
        {
            const float4 b4 = *(const float4*)&b1[c0];
            z[0][0]=b4.x; z[0][1]=b4.y; z[0][2]=b4.z; z[0][3]=b4.w;
            z[1][0]=b4.x; z[1][1]=b4.y; z[1][2]=b4.z; z[1][3]=b4.w;
        }
        #pragma unroll 2
        for (int s = 0; s < 67; ++s) {
            int i = s + irot; if (i >= 67) i -= 67;
            const float2 xf = *(const float2*)&sX[i*16 + 2*rg];
            const float4 wA = *(const float4*)&W1[(size_t)i*Hn + c0];
            const float ww[4] = {wA.x, wA.y, wA.z, wA.w};
            #pragma unroll
            for (int j = 0; j < 4; ++j) {
                z[0][j] = fmaf(xf.x, ww[j], z[0][j]);
                z[1][j] = fmaf(xf.y, ww[j], z[1][j]);
            }
        }
        const int kgrp = cg >> 1, joff = (cg & 1)*4;
        #pragma unroll
        for (int rr = 0; rr < 2; ++rr) {
            const int r = 2*(lane & 7) + rr;
            ushort4 phi, plo, ps;
            unsigned short* PH = (unsigned short*)&phi;
            unsigned short* PL = (unsigned short*)&plo;
            unsigned short* PS = (unsigned short*)&ps;
            #pragma unroll
            for (int j = 0; j < 4; ++j) {
                const float zv = z[rr][j];
                const float sg = 1.f / (1.f + __expf(-zv));
                const float h  = zv * sg;
                const float sp = sg * (1.f + zv * (1.f - sg));
                const unsigned short hh = f2bf(h);
                PH[j] = hh;
                PL[j] = f2bf(h - bf2f(hh));
                PS[j] = f2bf(sp);
            }
            const int off = (wv*64 + r + 16*kgrp)*8 + joff;
            *(ushort4*)&sA[off]         = phi;
            *(ushort4*)&sA[8192 + off]  = plo;
            *(ushort4*)&sA[16384 + off] = ps;
        }
    }
    __syncthreads();

    // ---- phase B: z2/v MFMA; wave wv -> ctiles {wv*2, wv*2+1}; rotated ks;
    //      explicit double-buffered weight prefetch (vmcnt never drains to 0) ----
    const int ctb = wv*2;
    f32x4 zac[2], vac[2];
    #pragma unroll
    for (int ti = 0; ti < 2; ++ti) {
        const float bz = b2[(ctb + ti)*16 + n];
        zac[ti] = (f32x4){bz, bz, bz, bz};
        vac[ti] = (f32x4){0.f, 0.f, 0.f, 0.f};
    }
    short8 wbuf[2][2], qbuf[2][2];
    #pragma unroll
    for (int ti = 0; ti < 2; ++ti) {
        const size_t wo = ((size_t)((ctb + ti)*16 + rot)*64 + lane)*16;
        wbuf[0][ti] = *(const short8*)&WQ[wo];
        qbuf[0][ti] = *(const short8*)&WQ[wo + 8];
    }
    #pragma unroll
    for (int s = 0; s < 16; ++s) {
        const int cur = s & 1, nxt = cur ^ 1;
        if (s < 15) {
            const int ksn = (s + 1 + rot) & 15;
            #pragma unroll
            for (int ti = 0; ti < 2; ++ti) {
                const size_t wo = ((size_t)((ctb + ti)*16 + ksn)*64 + lane)*16;
                wbuf[nxt][ti] = *(const short8*)&WQ[wo];
                qbuf[nxt][ti] = *(const short8*)&WQ[wo + 8];
            }
        }
        const int ks = (s + rot) & 15;
        const int ao = (ks*64 + lane)*8;
        const short8 ahi = *(const short8*)&sA[ao];
        const short8 alo = *(const short8*)&sA[8192 + ao];
        const short8 as1 = *(const short8*)&sA[16384 + ao];
        #pragma unroll
        for (int ti = 0; ti < 2; ++ti) {
            zac[ti] = __builtin_amdgcn_mfma_f32_16x16x32_bf16(ahi, wbuf[cur][ti], zac[ti], 0, 0, 0);
            zac[ti] = __builtin_amdgcn_mfma_f32_16x16x32_bf16(alo, wbuf[cur][ti], zac[ti], 0, 0, 0);
            vac[ti] = __builtin_amdgcn_mfma_f32_16x16x32_bf16(as1, qbuf[cur][ti], vac[ti], 0, 0, 0);
        }
    }
    __syncthreads();   // all sA reads complete before h2 aliases it

    // ---- epilogue: h2 hi/lo -> sA[0..8192]/sA[8192..]; divergence partials ----
    float dp[4] = {0.f, 0.f, 0.f, 0.f};
    #pragma unroll
    for (int ti = 0; ti < 2; ++ti) {
        const int c = (ctb + ti)*16 + n;
        const int ks2 = c >> 5, kg2 = (c >> 3) & 3, j2 = c & 7;
        #pragma unroll
        for (int q = 0; q < 4; ++q) {
            const float z2 = zac[ti][q];
            const float sg = 1.f / (1.f + __expf(-z2));
            const float h2 = z2 * sg;
            dp[q] = fmaf(sg * (1.f + z2 * (1.f - sg)), vac[ti][q], dp[q]);
            const unsigned short hh = f2bf(h2);
            const int o = (ks2*64 + (kg*4 + q) + 16*kg2)*8 + j2;
            sA[o] = hh;
            sA[8192 + o] = f2bf(h2 - bf2f(hh));
        }
    }
    #pragma unroll
    for (int q = 0; q < 4; ++q) {
        float v = dp[q];
        v += __shfl_xor(v, 1, 64);
        v += __shfl_xor(v, 2, 64);
        v += __shfl_xor(v, 4, 64);
        v += __shfl_xor(v, 8, 64);
        if (n == 0) sRed[wv*16 + kg*4 + q] = v;
    }
    __syncthreads();

    // ---- divergence finalize ----
    if (tid < 16) {
        float s = 0.f;
        #pragma unroll
        for (int q = 0; q < 16; ++q) s += sRed[q*16 + tid];
        out[(size_t)Bn*Dn + r0 + tid] = -s;
    }

    // ---- phase C: out = h2 @ W3 + b3 (waves 0..4); rotated ks ----
    if (wv < 5) {
        const int jt = wv;
        const int j = jt*16 + n;
        const float bj = (j < Dn) ? b3[j] : 0.f;
        f32x4 oac = (f32x4){bj, bj, bj, bj};
        #pragma unroll 4
        for (int s = 0; s < 16; ++s) {
            const int ks = (s + rot) & 15;
            const int aoff = (ks*64 + lane)*8;
            const short8 ahi = *(const short8*)&sA[aoff];
            const short8 alo = *(const short8*)&sA[8192 + aoff];
            const short8 wf  = *(const short8*)&W3P[((size_t)(jt*16 + ks)*64 + lane)*8];
            oac = __builtin_amdgcn_mfma_f32_16x16x32_bf16(ahi, wf, oac, 0, 0, 0);
            oac = __builtin_amdgcn_mfma_f32_16x16x32_bf16(alo, wf, oac, 0, 0, 0);
        }
        if (j < Dn) {
            #pragma unroll
            for (int q = 0; q < 4; ++q)
                out[(size_t)(r0 + kg*4 + q)*Dn + j] = oac[q];
        }
    }
}

extern "C" void kernel_launch(void* const* d_in, const int* in_sizes, int n_in,
                              void* d_out, int out_size, void* d_ws, size_t ws_size,
                              hipStream_t stream)
{
    const float* xs = (const float*)d_in[0];
    const float* t  = (const float*)d_in[1];
    const float* W1 = (const float*)d_in[2];
    const float* b1 = (const float*)d_in[3];
    const float* W2 = (const float*)d_in[4];
    const float* b2 = (const float*)d_in[5];
    const float* W3 = (const float*)d_in[6];
    const float* b3 = (const float*)d_in[7];
    float* out = (float*)d_out;

    char* ws = (char*)d_ws;
    unsigned short* WQ  = (unsigned short*)(ws);                 // 1 MB interleaved W2|Cm
    unsigned short* W3P = (unsigned short*)(ws + 1048576);       // 80 KB

    k_pack<<<74,  512,  0, stream>>>(W1, W2, W3, WQ, W3P);
    k_main<<<256, 1024, 0, stream>>>(xs, t, W1, b1, WQ, b2, W3P, b3, out);
}